// Round 9
// baseline (198.403 us; speedup 1.0000x reference)
//
#include <hip/hip_runtime.h>
#include <hip/hip_bf16.h>

// PrototypeConsistentLearning: loss = mean(-pos + lse_neg), new_protos = serial EMA.
// B=8192, D=512, K=16384, T=0.5, momentum=0.9.
// R15: occupancy-first flash. R14 closed the books: matrix work = 71k cy/CU but
// wall = 188k cy; 2 waves/SIMD (192 unified regs: afr 128 + acc 64) can't cover
// per-wave non-MFMA issue (VALU 31%, exp bursts, ds latency, barrier drain).
// Fix: wave M=32 (afr[4][2]=64 regs) + COLUMN-MAJOR steps: each step stages 32
// proto-rows x full K=512 (16 KB, same buffer), completes the K-reduction ->
// per-step acc = 4 named floatx4 (16 regs), exp spread evenly (16/step).
// Total ~120 regs <= 128 -> __launch_bounds__(256,4) = 4 blocks/CU, 16 waves.
// Cost: B in-reg reuse halves -> LDS-read pipe ~98-130k cy/CU = new floor
// (~45-55us), still << R14's 188k. Same XOR granule swizzle (bank math
// unchanged: ch*128 = 0 mod 32 banks), same 1-syncthreads/step staging, same
// XCD-pinned K-split (wgl&7). pos/EMA exact fp32, unchanged.

#define B_N 8192
#define D_N 512
#define K_N 16384
#define INV_T 2.0f
#define MOM 0.9f

#define BM 128          // A rows per block; wave owns 32
#define KSPLIT 8        // each block covers K_N/KSPLIT = 2048 proto rows
#define NSTEP 64        // col-steps per block (2048 / 32)
#define BUFB 16384      // bytes per B buffer (32 rows x 512 B)
#define CAP 64

typedef __attribute__((ext_vector_type(8))) int intx8;
typedef __attribute__((ext_vector_type(4))) float floatx4;

__device__ __forceinline__ void gl_lds16(const void* g, void* lds) {
    __builtin_amdgcn_global_load_lds(
        (const __attribute__((address_space(1))) void*)g,
        (__attribute__((address_space(3))) void*)lds, 16, 0, 0);
}

__device__ __forceinline__ intx8 frag2(const unsigned char* rp, int o0, int o1) {
    intx8 v;
    ((int4*)&v)[0] = *(const int4*)(rp + o0);
    ((int4*)&v)[1] = *(const int4*)(rp + o1);
    return v;
}

__device__ __forceinline__ floatx4 mxfma(intx8 a, intx8 b, floatx4 c) {
    return __builtin_amdgcn_mfma_scale_f32_16x16x128_f8f6f4(a, b, c, 0, 0, 0,
                                                            0x7F7F7F7F, 0, 0x7F7F7F7F);
}

// ---- normalize rows (fp32) -> e4m3 fp8 scaled by 16; also zero rowsum/out[0]. ----
__global__ void norm_kernel(const float* __restrict__ emb, const float* __restrict__ pro,
                            unsigned char* __restrict__ embq, unsigned char* __restrict__ proq,
                            float* __restrict__ rowsum, float* __restrict__ out) {
    if (blockIdx.x < 32) rowsum[blockIdx.x * 256 + threadIdx.x] = 0.0f;
    if (blockIdx.x == 32 && threadIdx.x == 0) out[0] = 0.0f;
    int row = blockIdx.x * 4 + (threadIdx.x >> 6);
    int lane = threadIdx.x & 63;
    const float* x;
    unsigned char* o;
    if (row < B_N) {
        x = emb + (size_t)row * D_N;
        o = embq + (size_t)row * D_N;
    } else {
        x = pro + (size_t)(row - B_N) * D_N;
        o = proq + (size_t)(row - B_N) * D_N;
    }
    const float4* xp = (const float4*)(x + lane * 8);
    float4 v0 = xp[0];
    float4 v1 = xp[1];
    float ss = v0.x * v0.x + v0.y * v0.y + v0.z * v0.z + v0.w * v0.w +
               v1.x * v1.x + v1.y * v1.y + v1.z * v1.z + v1.w * v1.w;
    #pragma unroll
    for (int of = 32; of; of >>= 1) ss += __shfl_xor(ss, of);
    float sc = 16.0f / fmaxf(sqrtf(ss), 1e-12f);  // x16: e4m3 keeps full mantissa range
    int w0 = 0, w1 = 0;
    w0 = __builtin_amdgcn_cvt_pk_fp8_f32(v0.x * sc, v0.y * sc, w0, false);
    w0 = __builtin_amdgcn_cvt_pk_fp8_f32(v0.z * sc, v0.w * sc, w0, true);
    w1 = __builtin_amdgcn_cvt_pk_fp8_f32(v1.x * sc, v1.y * sc, w1, false);
    w1 = __builtin_amdgcn_cvt_pk_fp8_f32(v1.z * sc, v1.w * sc, w1, true);
    int2 st = {w0, w1};
    *(int2*)(o + lane * 8) = st;
}

// ---- pos[b] = 2 * dot(emb[b],pro[c]) / (|emb[b]| |pro[c]|), pure fp32 (exact). ----
__global__ void pos_kernel(const float* __restrict__ emb, const float* __restrict__ pro,
                           const int* __restrict__ cid, float* __restrict__ rowpos) {
    int b = blockIdx.x * 4 + (threadIdx.x >> 6);
    int lane = threadIdx.x & 63;
    int c = cid[b];
    const float4* ep = (const float4*)(emb + (size_t)b * D_N + lane * 8);
    const float4* pp = (const float4*)(pro + (size_t)c * D_N + lane * 8);
    float4 e0 = ep[0], e1 = ep[1], p0 = pp[0], p1 = pp[1];
    float dp = e0.x * p0.x + e0.y * p0.y + e0.z * p0.z + e0.w * p0.w +
               e1.x * p1.x + e1.y * p1.y + e1.z * p1.z + e1.w * p1.w;
    float ee = e0.x * e0.x + e0.y * e0.y + e0.z * e0.z + e0.w * e0.w +
               e1.x * e1.x + e1.y * e1.y + e1.z * e1.z + e1.w * e1.w;
    float qq = p0.x * p0.x + p0.y * p0.y + p0.z * p0.z + p0.w * p0.w +
               p1.x * p1.x + p1.y * p1.y + p1.z * p1.z + p1.w * p1.w;
    #pragma unroll
    for (int o = 32; o; o >>= 1) {
        dp += __shfl_xor(dp, o);
        ee += __shfl_xor(ee, o);
        qq += __shfl_xor(qq, o);
    }
    if (lane == 0)
        rowpos[b] = INV_T * dp / (fmaxf(sqrtf(ee), 1e-12f) * fmaxf(sqrtf(qq), 1e-12f));
}

// ---- flash GEMM (MX-fp8, col-major steps, A in regs, 4 blocks/CU):
//      rowsum[b] += sum_k exp(2*dot(emb_n[b], proto_n[k]))  ----
__global__ __launch_bounds__(256, 4) void flash_kernel(const unsigned char* __restrict__ embq,
                                                       const unsigned char* __restrict__ proq,
                                                       float* __restrict__ rowsum_g) {
    __shared__ __align__(16) unsigned char Bs[2 * BUFB];  // 32 KB, double-buffered
    const int t = threadIdx.x;
    const int w = t >> 6, lane = t & 63;
    const int quad = lane >> 4, lcol = lane & 15;

    // XCD-pinned K-split: wgid%8 round-robins XCDs -> each XCD's 1 MB proq slice
    // is L2-resident (proven R13/R14: FETCH 35 -> 16-20 MB).
    const int wgl = blockIdx.x;          // 0..511
    const int ks = wgl & 7;              // K-split 0..7
    const int rowBase = (wgl >> 3) * BM; // row-block 0..63
    const int kb = ks * (K_N / KSPLIT);

    // Fragment granule offsets: logical granules quad*2, quad*2+1 within a 128-B
    // D-chunk of a row; stored slot = granule ^ (row&7); frag rows have
    // row&7 == lcol&7. Bank math: ch*128 and row*512 are 0 mod 32-banks, so the
    // swizzle behavior is identical to the proven row-major layout.
    const int fsw0 = (((quad << 1) | 0) ^ (lcol & 7)) << 4;
    const int fsw1 = (((quad << 1) | 1) ^ (lcol & 7)) << 4;

    // Staging (col-major): pass p writes step-tile rows p*8 + w*2 + (lane>>5),
    // granule g = lane&31; stored slot g&7 holds source granule (g&7)^(row&7).
    const int srow = w * 2 + (lane >> 5);            // 0..7, invariant across passes
    const int g = lane & 31;
    const unsigned char* bS = proq + (size_t)(kb + srow) * D_N + ((g >> 3) << 7) +
                              (((g & 7) ^ (srow & 7)) << 4);

    float rs[8];
    #pragma unroll
    for (int i = 0; i < 8; i++) rs[i] = 0.0f;

    // ---- prologue: A frags direct from global (16 dwordx4 -> 64 VGPR: wave rows
    //      w*32..+32, all K), then stage step 0 -> buf0; syncthreads drains all. ----
    intx8 afr[4][2];
    {
        const unsigned char* aBase =
            embq + (size_t)(rowBase + w * 32 + lcol) * D_N + quad * 32;
        #pragma unroll
        for (int ch = 0; ch < 4; ch++)
            #pragma unroll
            for (int mi = 0; mi < 2; mi++) {
                const unsigned char* p = aBase + (size_t)mi * (16 * D_N) + (ch << 7);
                ((int4*)&afr[ch][mi])[0] = *(const int4*)(p);
                ((int4*)&afr[ch][mi])[1] = *(const int4*)(p + 16);
            }
    }
    #pragma unroll
    for (int p = 0; p < 4; p++)
        gl_lds16(bS + (size_t)p * 8 * D_N, Bs + p * 4096 + w * 1024);
    __syncthreads();

    const unsigned char* bSrc = bS + (size_t)32 * D_N;  // step-1 source
    for (int s = 0; s < NSTEP; s++) {
        // stage step s+1 into the other buffer (freed by the barrier ending s-1)
        if (s + 1 < NSTEP) {
            unsigned char* d = Bs + ((s + 1) & 1) * BUFB + w * 1024;
            #pragma unroll
            for (int p = 0; p < 4; p++)
                gl_lds16(bSrc + (size_t)p * 8 * D_N, d + p * 4096);
        }
        bSrc += (size_t)32 * D_N;

        // full K-reduction for 32 proto-rows: 16 MFMAs, acc in 4 named regs
        const unsigned char* rb0 = Bs + (s & 1) * BUFB + lcol * 512;  // nf=0
        const unsigned char* rb1 = rb0 + 16 * 512;                    // nf=1
        floatx4 a00 = {0.f, 0.f, 0.f, 0.f}, a01 = {0.f, 0.f, 0.f, 0.f};
        floatx4 a10 = {0.f, 0.f, 0.f, 0.f}, a11 = {0.f, 0.f, 0.f, 0.f};
        __builtin_amdgcn_s_setprio(1);
        #pragma unroll
        for (int ch = 0; ch < 4; ch++) {
            intx8 b0 = frag2(rb0 + (ch << 7), fsw0, fsw1);
            intx8 b1 = frag2(rb1 + (ch << 7), fsw0, fsw1);
            a00 = mxfma(afr[ch][0], b0, a00);
            a01 = mxfma(afr[ch][0], b1, a01);
            a10 = mxfma(afr[ch][1], b0, a10);
            a11 = mxfma(afr[ch][1], b1, a11);
        }
        __builtin_amdgcn_s_setprio(0);

        // per-step epilogue: 16 exps (evenly spread), un-scale 16*16 -> 2^-8
        #pragma unroll
        for (int r = 0; r < 4; r++) {
            rs[r] += __expf(a00[r] * (INV_T / 256.0f)) + __expf(a01[r] * (INV_T / 256.0f));
            rs[4 + r] += __expf(a10[r] * (INV_T / 256.0f)) + __expf(a11[r] * (INV_T / 256.0f));
        }

        __syncthreads();  // stage s+1 landed + all waves done reading buf s&1
    }

    // C/D layout: col=lane&15, row=quad*4+r. rs[mi*4+r] = partial sum for row
    // rowBase + w*32 + mi*16 + quad*4 + r over this lane's cols; reduce over the
    // 16 lcol lanes (within the quad), then one atomic per row.
    #pragma unroll
    for (int i = 0; i < 8; i++) {
        #pragma unroll
        for (int o = 1; o < 16; o <<= 1) rs[i] += __shfl_xor(rs[i], o);
    }
    if (lcol == 0) {
        #pragma unroll
        for (int mi = 0; mi < 2; mi++)
            #pragma unroll
            for (int r = 0; r < 4; r++)
                atomicAdd(&rowsum_g[rowBase + w * 32 + mi * 16 + quad * 4 + r],
                          rs[mi * 4 + r]);
    }
}

// ---- loss partial: 32 blocks, atomicAdd into out[0]; also zero cnt for EMA. ----
__global__ void loss_kernel(const float* __restrict__ rowsum, const float* __restrict__ rowpos,
                            float* __restrict__ out, int* __restrict__ cnt) {
    __shared__ float red[256];
    int t = threadIdx.x;
    int b = blockIdx.x * 256 + t;
    cnt[b * 2] = 0;
    cnt[b * 2 + 1] = 0;
    float p = rowpos[b];
    red[t] = logf(rowsum[b] - __expf(p)) - p;
    __syncthreads();
    for (int o = 128; o; o >>= 1) {
        if (t < o) red[t] += red[t + o];
        __syncthreads();
    }
    if (t == 0) atomicAdd(out, red[0] * (1.0f / (float)B_N));
}

// ---- EMA phase 1: bucket occurrence indices per cluster. ----
__global__ void ema_count(const int* __restrict__ cid, int* __restrict__ cnt,
                          int* __restrict__ bucket) {
    int b = blockIdx.x * 256 + threadIdx.x;
    int c = cid[b];
    int slot = atomicAdd(&cnt[c], 1);
    if (slot < CAP) bucket[c * CAP + slot] = b;
}

// ---- EMA phase 2: one wave per cluster, replay occurrences in ascending b. ----
__global__ void ema_apply(const float* __restrict__ emb, const float* __restrict__ pro,
                          const int* __restrict__ cnt, const int* __restrict__ bucket,
                          float* __restrict__ outp) {
    int k = blockIdx.x * 4 + (threadIdx.x >> 6);
    int lane = threadIdx.x & 63;
    int n = cnt[k];
    n = n < CAP ? n : CAP;
    const float4* pp = (const float4*)(pro + (size_t)k * D_N + lane * 8);
    float4 a0 = pp[0], a1 = pp[1];
    int myb = (lane < n) ? bucket[k * CAP + lane] : 0x7fffffff;
    for (int i = 0; i < n; i++) {
        int m = myb;
        #pragma unroll
        for (int o = 1; o < 64; o <<= 1) {
            int v = __shfl_xor(m, o);
            m = v < m ? v : m;
        }
        const float4* ep = (const float4*)(emb + (size_t)m * D_N + lane * 8);
        float4 e0 = ep[0], e1 = ep[1];
        a0.x = MOM * a0.x + (1.0f - MOM) * e0.x;
        a0.y = MOM * a0.y + (1.0f - MOM) * e0.y;
        a0.z = MOM * a0.z + (1.0f - MOM) * e0.z;
        a0.w = MOM * a0.w + (1.0f - MOM) * e0.w;
        a1.x = MOM * a1.x + (1.0f - MOM) * e1.x;
        a1.y = MOM * a1.y + (1.0f - MOM) * e1.y;
        a1.z = MOM * a1.z + (1.0f - MOM) * e1.z;
        a1.w = MOM * a1.w + (1.0f - MOM) * e1.w;
        if (myb == m) myb = 0x7fffffff;
    }
    float4* op = (float4*)(outp + (size_t)k * D_N + lane * 8);
    op[0] = a0;
    op[1] = a1;
}

extern "C" void kernel_launch(void* const* d_in, const int* in_sizes, int n_in,
                              void* d_out, int out_size, void* d_ws, size_t ws_size,
                              hipStream_t stream) {
    const float* emb = (const float*)d_in[0];
    const int* cid = (const int*)d_in[1];
    const float* pro = (const float*)d_in[2];
    float* out = (float*)d_out;

    char* ws = (char*)d_ws;
    unsigned char* embq = (unsigned char*)ws;                      // 4 MB fp8 [B,D]
    unsigned char* proq = (unsigned char*)(ws + 4194304);          // 8 MB fp8 [K,D]
    float* rowsum = (float*)(ws + 12582912);                       // [B]
    float* rowpos = (float*)(ws + 12615680);                       // [B]
    // EMA buckets alias the proq region — only touched after flash_kernel (stream
    // order): loss_kernel zeroes cnt, ema_count fills, ema_apply reads.
    int* cnt = (int*)(ws + 4194304);                               // [K]
    int* bucket = (int*)(ws + 4194304 + 65536);                    // [K, CAP]

    norm_kernel<<<(B_N + K_N) / 4, 256, 0, stream>>>(emb, pro, embq, proq, rowsum, out);
    pos_kernel<<<B_N / 4, 256, 0, stream>>>(emb, pro, cid, rowpos);
    flash_kernel<<<dim3(64 * KSPLIT), 256, 0, stream>>>(embq, proq, rowsum);
    loss_kernel<<<B_N / 256, 256, 0, stream>>>(rowsum, rowpos, out, cnt);
    ema_count<<<B_N / 256, 256, 0, stream>>>(cid, cnt, bucket);
    ema_apply<<<K_N / 4, 256, 0, stream>>>(emb, pro, cnt, bucket, out + 1);
}